// Round 1
// baseline (12575.988 us; speedup 1.0000x reference)
//
#include <hip/hip_runtime.h>
#include <cstdint>
#include <cstddef>

// GRU decoder: LAYERS=3, UNITS=1024, B=128, T=256, reset_after=True.
// Strategy R1: fp16 MFMA everywhere (fp32 accum), per-layer big x-projection
// GEMM (m97 structure), 256 fused per-step recurrence kernels per layer.

#define UNITS 1024
#define U3 3072
#define BATCH 128
#define TSTEPS 256

typedef _Float16 h16;
typedef __attribute__((ext_vector_type(8))) _Float16 h16x8;
typedef __attribute__((ext_vector_type(4))) _Float16 h16x4;
typedef __attribute__((ext_vector_type(4))) float f32x4;

#define GAS __attribute__((address_space(1)))
#define LAS __attribute__((address_space(3)))
#define ASYNC16(g, l) __builtin_amdgcn_global_load_lds((const GAS unsigned int*)(g), (LAS unsigned int*)(l), 16, 0, 0)

__device__ __forceinline__ float sigmf(float x) { return 1.0f / (1.0f + __expf(-x)); }
__device__ __forceinline__ float tanhf_fast(float x) { return 2.0f / (1.0f + __expf(-2.0f * x)) - 1.0f; }

// input_seq [B,T,U] f32 -> x16 [T,B,U] f16  (t-major so per-step slices are contiguous)
__global__ void k_cvt_x(const float* __restrict__ x, h16* __restrict__ xo) {
  const int m = blockIdx.x;            // out row = t*128 + b
  const int t = m >> 7, b = m & 127;
  const int u = threadIdx.x << 2;
  const float4 v = *(const float4*)(x + (size_t)((b << 8) + t) * UNITS + u);
  h16x4 o; o[0] = (h16)v.x; o[1] = (h16)v.y; o[2] = (h16)v.z; o[3] = (h16)v.w;
  *(h16x4*)(xo + (size_t)m * UNITS + u) = o;
}

// src [3][1024][3072] f32 -> dst [3][3072][1024] f16 (transpose: K-contiguous "B^T" layout)
__global__ void k_trans(const float* __restrict__ src, h16* __restrict__ dst) {
  __shared__ float sT[32][33];
  const int l = blockIdx.z;
  const int n0 = blockIdx.x << 5, k0 = blockIdx.y << 5;
  const int tx = threadIdx.x, ty = threadIdx.y;   // 32 x 8
  const float* s = src + (size_t)l * UNITS * U3;
  h16* d = dst + (size_t)l * U3 * UNITS;
#pragma unroll
  for (int r = 0; r < 4; ++r)
    sT[ty + r * 8][tx] = s[(size_t)(k0 + ty + r * 8) * U3 + n0 + tx];
  __syncthreads();
#pragma unroll
  for (int r = 0; r < 4; ++r)
    d[(size_t)(n0 + ty + r * 8) * UNITS + k0 + tx] = (h16)sT[tx][ty + r * 8];
}

// initial_states [B,U,3] f32 -> h0 [3][B*U] f16
__global__ void k_cvt_h(const float* __restrict__ init, h16* __restrict__ h0) {
  const int idx = blockIdx.x * 256 + threadIdx.x;  // < 3*131072
  const int l = idx >> 17, r = idx & 131071;
  h0[idx] = (h16)init[(size_t)r * 3 + l];
}

// C[M,3072] = A[M,1024] @ Bt[3072,1024]^T + bias  (all f16 in, f32 acc, f16 out)
// m97 structure: 128x128 tile, BK=32, 4 waves 2x2, global_load_lds width 16.
__global__ __launch_bounds__(256) void k_gemm_xw(
    const h16* __restrict__ A, const h16* __restrict__ Bt,
    const float* __restrict__ bias, h16* __restrict__ C) {
  __shared__ __align__(16) h16 sA[128 * 32];
  __shared__ __align__(16) h16 sB[128 * 32];
  const int tid = threadIdx.x;
  const int lane = tid & 63, wave = tid >> 6;
  const int wm = (wave & 1) << 6, wn = (wave >> 1) << 6;
  const int m0 = blockIdx.x << 7;
  const int n0 = blockIdx.y << 7;
  const int crow = tid >> 2, ck = (tid & 3) << 3;
  const int fm = lane & 15, fq = lane >> 4;
  f32x4 acc[4][4] = {};
  for (int k0 = 0; k0 < 1024; k0 += 32) {
    ASYNC16(A + (size_t)(m0 + crow) * 1024 + k0 + ck,      sA + wave * 512);
    ASYNC16(A + (size_t)(m0 + 64 + crow) * 1024 + k0 + ck, sA + 2048 + wave * 512);
    ASYNC16(Bt + (size_t)(n0 + crow) * 1024 + k0 + ck,      sB + wave * 512);
    ASYNC16(Bt + (size_t)(n0 + 64 + crow) * 1024 + k0 + ck, sB + 2048 + wave * 512);
    __syncthreads();
    h16x8 af[4], bfv[4];
#pragma unroll
    for (int i = 0; i < 4; ++i)
      af[i] = *(const h16x8*)(sA + (wm + i * 16 + fm) * 32 + fq * 8);
#pragma unroll
    for (int j = 0; j < 4; ++j)
      bfv[j] = *(const h16x8*)(sB + (wn + j * 16 + fm) * 32 + fq * 8);
#pragma unroll
    for (int i = 0; i < 4; ++i)
#pragma unroll
      for (int j = 0; j < 4; ++j)
        acc[i][j] = __builtin_amdgcn_mfma_f32_16x16x32_f16(af[i], bfv[j], acc[i][j], 0, 0, 0);
    __syncthreads();
  }
#pragma unroll
  for (int j = 0; j < 4; ++j) {
    const int col = n0 + wn + j * 16 + fm;
    const float bv = bias[col];
#pragma unroll
    for (int i = 0; i < 4; ++i) {
      const int row = m0 + wm + i * 16 + fq * 4;
#pragma unroll
      for (int r = 0; r < 4; ++r)
        C[(size_t)(row + r) * U3 + col] = (h16)(acc[i][j][r] + bv);
    }
  }
}

// One recurrence step, fused GEMM + gates.
// 64 blocks x 512 threads; block owns 16 h-cols (48 hu-cols); wave owns 16 rows.
// U^T slice staged to LDS in MFMA-fragment order (lane-linear, conflict-free).
__global__ __launch_bounds__(512) void k_step(
    const h16* __restrict__ Ut,    // [3072][1024] for this layer
    const float* __restrict__ b1,  // [3072]
    const h16* __restrict__ xw,    // [128][3072] slice at t
    const h16* __restrict__ h_in,  // [128][1024]
    h16* __restrict__ h_out,       // [128][1024]
    h16* __restrict__ y16,         // [128][1024] at t (next-layer input) or null
    float* __restrict__ yf,        // d_out x region [B,T,U] or null
    float* __restrict__ st,        // d_out states + l (stride 3)
    const int t) {
  __shared__ __align__(16) h16 sU[24576];  // 48KB: [16 kk][3 g][64 lane][8]
  const int tid = threadIdx.x;
  const int lane = tid & 63, wave = tid >> 6;
  const int c0 = blockIdx.x << 4;
  const int r0 = wave << 4;
  const int fm = lane & 15, fq = lane >> 4;
  f32x4 acc[3] = {};
  for (int s = 0; s < 2; ++s) {
    const int kb = s << 9;
#pragma unroll
    for (int i = 0; i < 6; ++i) {
      const int c = (i << 9) + tid;     // chunk id, 3072 chunks of 16B per stage
      const int l2 = c & 63;
      const int kg = c >> 6;            // 0..47 = kk*3+g
      const int kk = kg / 3;
      const int g = kg - kk * 3;
      ASYNC16(Ut + (size_t)((g << 10) + c0 + (l2 & 15)) * 1024 + kb + (kk << 5) + ((l2 >> 4) << 3),
              sU + (size_t)((i << 9) + (wave << 6)) * 8);
    }
    __syncthreads();
#pragma unroll
    for (int kk = 0; kk < 16; ++kk) {
      const h16x8 a = *(const h16x8*)(h_in + (size_t)(r0 + fm) * 1024 + kb + (kk << 5) + (fq << 3));
      const h16* bb = sU + (size_t)(kk * 3) * 512;
      const h16x8 bz8 = *(const h16x8*)(bb + lane * 8);
      const h16x8 br8 = *(const h16x8*)(bb + 512 + lane * 8);
      const h16x8 bh8 = *(const h16x8*)(bb + 1024 + lane * 8);
      acc[0] = __builtin_amdgcn_mfma_f32_16x16x32_f16(a, bz8, acc[0], 0, 0, 0);
      acc[1] = __builtin_amdgcn_mfma_f32_16x16x32_f16(a, br8, acc[1], 0, 0, 0);
      acc[2] = __builtin_amdgcn_mfma_f32_16x16x32_f16(a, bh8, acc[2], 0, 0, 0);
    }
    __syncthreads();
  }
  const int col = c0 + fm;
  const float bz = b1[col], br = b1[1024 + col], bh = b1[2048 + col];
#pragma unroll
  for (int r = 0; r < 4; ++r) {
    const int row = r0 + fq * 4 + r;          // C/D layout: col=lane&15, row=(lane>>4)*4+reg
    const float hp = (float)h_in[(size_t)row * 1024 + col];
    const float xz = (float)xw[(size_t)row * U3 + col];
    const float xr = (float)xw[(size_t)row * U3 + 1024 + col];
    const float xh = (float)xw[(size_t)row * U3 + 2048 + col];
    const float z  = sigmf(xz + acc[0][r] + bz);
    const float rg = sigmf(xr + acc[1][r] + br);
    const float hh = tanhf_fast(xh + rg * (acc[2][r] + bh));
    const float hn = z * hp + (1.0f - z) * hh;
    h_out[(size_t)row * 1024 + col] = (h16)hn;
    if (y16) y16[(size_t)row * 1024 + col] = (h16)hn;
    if (yf) yf[(size_t)(row * 256 + t) * 1024 + col] = hn;
    if (t == 255) st[(size_t)(row * 1024 + col) * 3] = hn;
  }
}

extern "C" void kernel_launch(void* const* d_in, const int* in_sizes, int n_in,
                              void* d_out, int out_size, void* d_ws, size_t ws_size,
                              hipStream_t stream) {
  const float* x_in  = (const float*)d_in[0];   // [128,256,1024]
  const float* h0_in = (const float*)d_in[1];   // [128,1024,3]
  const float* W     = (const float*)d_in[2];   // [3,1024,3072]
  const float* U     = (const float*)d_in[3];   // [3,1024,3072]
  const float* bias  = (const float*)d_in[4];   // [3,2,3072]
  float* out = (float*)d_out;

  char* ws = (char*)d_ws;
  h16* x16 = (h16*)(ws);                         // 67,108,864 B   [T,B,U]
  h16* xw  = (h16*)(ws + 67108864);              // 201,326,592 B  [T,B,3U]
  h16* Wt  = (h16*)(ws + 268435456);             // 18,874,368 B   [3][3072][1024]
  h16* Ut  = (h16*)(ws + 287309824);             // 18,874,368 B   [3][3072][1024]
  h16* h0b = (h16*)(ws + 306184192);             // 786,432 B      [3][128*1024]
  h16* hpp = (h16*)(ws + 306970624);             // 262,144 B      ping-pong partner

  k_cvt_x<<<TSTEPS * BATCH, 256, 0, stream>>>(x_in, x16);
  k_trans<<<dim3(96, 32, 3), dim3(32, 8), 0, stream>>>(W, Wt);
  k_trans<<<dim3(96, 32, 3), dim3(32, 8), 0, stream>>>(U, Ut);
  k_cvt_h<<<1536, 256, 0, stream>>>(h0_in, h0b);

  for (int l = 0; l < 3; ++l) {
    const float* b0 = bias + (size_t)l * 6144;
    const float* b1 = bias + (size_t)l * 6144 + 3072;
    k_gemm_xw<<<dim3(256, 24), 256, 0, stream>>>(x16, Wt + (size_t)l * U3 * UNITS, b0, xw);
    h16* hA = h0b + (size_t)l * BATCH * UNITS;
    h16* hB = hpp;
    for (int t = 0; t < TSTEPS; ++t) {
      h16* hin  = (t & 1) ? hB : hA;
      h16* hout = (t & 1) ? hA : hB;
      h16* y16p = (l < 2) ? (x16 + (size_t)t * BATCH * UNITS) : nullptr;
      float* yfp = (l == 2) ? out : nullptr;
      float* stp = out + 33554432 + l;
      k_step<<<64, 512, 0, stream>>>(Ut + (size_t)l * U3 * UNITS, b1,
                                     xw + (size_t)t * BATCH * U3,
                                     hin, hout, y16p, yfp, stp, t);
    }
  }
}